// Round 1
// baseline (1816.506 us; speedup 1.0000x reference)
//
#include <hip/hip_runtime.h>

#define S 128
#define R 384
#define CIN 256
#define H 8
#define D 32
#define CZ 128
#define E 256   // H*D

// ---------------------------------------------------------------------------
// K1: pair bias  pb[h][q][k] = sum_c LN(z[q][k][:])[c] * w_pair[c][h]
// one wave (64 lanes) per (q,k) pair; block = 4 waves
// ---------------------------------------------------------------------------
__global__ __launch_bounds__(256) void k_pairbias(
    const float* __restrict__ z, const float* __restrict__ lnw,
    const float* __restrict__ lnb, const float* __restrict__ wp,
    float* __restrict__ pb)
{
    int wid  = blockIdx.x * 4 + (threadIdx.x >> 6);
    int lane = threadIdx.x & 63;
    int qi = wid / R;
    int ki = wid - qi * R;
    const float* zr = z + (size_t)wid * CZ;
    float z0 = zr[lane], z1 = zr[lane + 64];
    float s  = z0 + z1;
    float sq = z0 * z0 + z1 * z1;
#pragma unroll
    for (int off = 32; off >= 1; off >>= 1) {
        s  += __shfl_xor(s, off);
        sq += __shfl_xor(sq, off);
    }
    float mu   = s * (1.0f / CZ);
    float var  = sq * (1.0f / CZ) - mu * mu;
    float rstd = rsqrtf(var + 1e-5f);
    float zl0 = (z0 - mu) * rstd * lnw[lane]      + lnb[lane];
    float zl1 = (z1 - mu) * rstd * lnw[lane + 64] + lnb[lane + 64];
    const float* w0 = wp + lane * H;
    const float* w1 = wp + (lane + 64) * H;
    float ph[H];
#pragma unroll
    for (int h = 0; h < H; h++) ph[h] = zl0 * w0[h] + zl1 * w1[h];
#pragma unroll
    for (int off = 32; off >= 1; off >>= 1) {
#pragma unroll
        for (int h = 0; h < H; h++) ph[h] += __shfl_xor(ph[h], off);
    }
    if (lane == 0) {
#pragma unroll
        for (int h = 0; h < H; h++)
            pb[((size_t)h * R + qi) * R + ki] = ph[h];
    }
}

// ---------------------------------------------------------------------------
// K2: fused LN(m) + Q/K/V/G projections. 32 rows per block, 256 threads.
// Thread register tile: 4 rows x 8 cols. q scaled by D^-0.5, g sigmoided.
// q/k/v layout [s][h][res][d]; g layout [row][e]
// ---------------------------------------------------------------------------
__global__ __launch_bounds__(256) void k_proj(
    const float* __restrict__ m, const float* __restrict__ lnw,
    const float* __restrict__ lnb,
    const float* __restrict__ wq, const float* __restrict__ wk,
    const float* __restrict__ wv, const float* __restrict__ wg,
    const float* __restrict__ bg,
    float* __restrict__ qb, float* __restrict__ kb,
    float* __restrict__ vb, float* __restrict__ gb)
{
    __shared__ float mt[32][260];
    __shared__ float red[2][8][32];
    __shared__ float muv[32][2];
    const int t = threadIdx.x;
    const int row0 = blockIdx.x * 32;

    // stage 32x256 m-tile
#pragma unroll
    for (int i = 0; i < 8; i++) {
        int off = (i * 256 + t) * 4;
        int r = off >> 8, c = off & 255;
        *(float4*)&mt[r][c] = *(const float4*)(m + (size_t)(row0 + r) * CIN + c);
    }
    __syncthreads();
    // LN stats: 8 threads per row
    {
        int r = t & 31, j = t >> 5;
        float s = 0.f, sq = 0.f;
#pragma unroll
        for (int i = 0; i < 32; i++) {
            float x = mt[r][j * 32 + i];
            s += x; sq += x * x;
        }
        red[0][j][r] = s; red[1][j][r] = sq;
    }
    __syncthreads();
    if (t < 32) {
        float s = 0.f, sq = 0.f;
#pragma unroll
        for (int j = 0; j < 8; j++) { s += red[0][j][t]; sq += red[1][j][t]; }
        float mu  = s * (1.0f / CIN);
        float var = sq * (1.0f / CIN) - mu * mu;
        muv[t][0] = mu;
        muv[t][1] = rsqrtf(var + 1e-5f);
    }
    __syncthreads();
    {
        float lw = lnw[t], lb = lnb[t];
#pragma unroll 4
        for (int r = 0; r < 32; r++) {
            float x = mt[r][t];
            mt[r][t] = (x - muv[r][0]) * muv[r][1] * lw + lb;
        }
    }
    __syncthreads();

    const int eg = t & 31, rg = t >> 5;
    const int e0 = eg * 8, r0 = rg * 4;
    const float* wmat[4] = {wq, wk, wv, wg};

    for (int mat = 0; mat < 4; mat++) {
        const float* __restrict__ w = wmat[mat];
        float acc[4][8];
#pragma unroll
        for (int i = 0; i < 4; i++)
#pragma unroll
            for (int jj = 0; jj < 8; jj++) acc[i][jj] = 0.f;

        for (int c = 0; c < CIN; c += 4) {
#pragma unroll
            for (int cc = 0; cc < 4; cc++) {
                const float* wrow = w + (size_t)(c + cc) * E + e0;
                float4 wlo = *(const float4*)wrow;
                float4 whi = *(const float4*)(wrow + 4);
                float wr[8] = {wlo.x, wlo.y, wlo.z, wlo.w,
                               whi.x, whi.y, whi.z, whi.w};
#pragma unroll
                for (int i = 0; i < 4; i++) {
                    float a = mt[r0 + i][c + cc];
#pragma unroll
                    for (int jj = 0; jj < 8; jj++)
                        acc[i][jj] = fmaf(a, wr[jj], acc[i][jj]);
                }
            }
        }
        if (mat == 0) {
#pragma unroll
            for (int i = 0; i < 4; i++)
#pragma unroll
                for (int jj = 0; jj < 8; jj++) acc[i][jj] *= 0.17677669529663687f;
        }
        if (mat == 3) {
#pragma unroll
            for (int i = 0; i < 4; i++)
#pragma unroll
                for (int jj = 0; jj < 8; jj++) {
                    float x = acc[i][jj] + bg[e0 + jj];
                    acc[i][jj] = 1.0f / (1.0f + __expf(-x));
                }
        }
        if (mat < 3) {
            float* dst = (mat == 0) ? qb : (mat == 1) ? kb : vb;
            int hh = e0 >> 5, d0 = e0 & 31;
#pragma unroll
            for (int i = 0; i < 4; i++) {
                int rw = row0 + r0 + i;
                int ss = rw / R, res = rw - ss * R;
                float* p = dst + (((size_t)ss * H + hh) * R + res) * D + d0;
                float4 lo = {acc[i][0], acc[i][1], acc[i][2], acc[i][3]};
                float4 hi = {acc[i][4], acc[i][5], acc[i][6], acc[i][7]};
                *(float4*)p = lo;
                *(float4*)(p + 4) = hi;
            }
        } else {
#pragma unroll
            for (int i = 0; i < 4; i++) {
                int rw = row0 + r0 + i;
                float* p = gb + (size_t)rw * E + e0;
                float4 lo = {acc[i][0], acc[i][1], acc[i][2], acc[i][3]};
                float4 hi = {acc[i][4], acc[i][5], acc[i][6], acc[i][7]};
                *(float4*)p = lo;
                *(float4*)(p + 4) = hi;
            }
        }
    }
}

// ---------------------------------------------------------------------------
// K3: attention. One block per (s,h). K,V in LDS (pad 36), logits tile P
// (32 q-rows x 384) bias-initialized, two-pass softmax, PV, gate in epilogue.
// LDS total 161536 B.
// ---------------------------------------------------------------------------
__global__ __launch_bounds__(256) void k_attn(
    const float* __restrict__ qb, const float* __restrict__ kb,
    const float* __restrict__ vb, const float* __restrict__ gb,
    const float* __restrict__ pb, const float* __restrict__ mask,
    float* __restrict__ ob)
{
    __shared__ float Ks[R][36];
    __shared__ float Vs[R][36];
    __shared__ float P[32][388];
    __shared__ float red[8][32];
    __shared__ float rowm[32];
    __shared__ float rowl[32];
    const int t = threadIdx.x;
    const int s = blockIdx.x >> 3;
    const int h = blockIdx.x & 7;
    const size_t kvbase = (size_t)(s * H + h) * R * D;

#pragma unroll
    for (int i = 0; i < 12; i++) {
        int off = (i * 256 + t) * 4;
        int r = off >> 5, d = off & 31;
        *(float4*)&Ks[r][d] = *(const float4*)(kb + kvbase + off);
        *(float4*)&Vs[r][d] = *(const float4*)(vb + kvbase + off);
    }
    const int rr = t & 31, j = t >> 5;
    __syncthreads();

    for (int qt = 0; qt < 12; qt++) {
        const int q0 = qt * 32;
        __syncthreads();   // previous tile's phase C done; P reusable
        // P init = pair bias + mask bias (coalesced)
        for (int idx = t; idx < 32 * R; idx += 256) {
            int r = idx / R, c = idx - r * R;
            P[r][c] = pb[((size_t)(h * R) + q0 + r) * R + c]
                    + 1e9f * (mask[s * R + c] - 1.0f);
        }
        // my q row (8 threads share a row; L1 absorbs the duplication)
        float qreg[32];
        const float* qrow = qb + kvbase + (size_t)(q0 + rr) * D;
#pragma unroll
        for (int i = 0; i < 8; i++)
            *(float4*)&qreg[i * 4] = *(const float4*)(qrow + i * 4);
        __syncthreads();
        // phase A: logits. thread (rr, j) does cols j*48..j*48+47
        for (int i = 0; i < 48; i++) {
            int c = j * 48 + i;
            float a0 = 0, a1 = 0, a2 = 0, a3 = 0;
#pragma unroll
            for (int d = 0; d < 32; d += 4) {
                a0 = fmaf(qreg[d + 0], Ks[c][d + 0], a0);
                a1 = fmaf(qreg[d + 1], Ks[c][d + 1], a1);
                a2 = fmaf(qreg[d + 2], Ks[c][d + 2], a2);
                a3 = fmaf(qreg[d + 3], Ks[c][d + 3], a3);
            }
            P[rr][c] += (a0 + a1) + (a2 + a3);
        }
        __syncthreads();
        // phase B: softmax (max pass)
        {
            float mx = -1e30f;
            for (int i = 0; i < 48; i++) mx = fmaxf(mx, P[rr][j * 48 + i]);
            red[j][rr] = mx;
        }
        __syncthreads();
        if (t < 32) {
            float mx = red[0][t];
#pragma unroll
            for (int jj = 1; jj < 8; jj++) mx = fmaxf(mx, red[jj][t]);
            rowm[t] = mx;
        }
        __syncthreads();
        {
            float mval = rowm[rr];
            float sum = 0.f;
            for (int i = 0; i < 48; i++) {
                int c = j * 48 + i;
                float p = __expf(P[rr][c] - mval);
                P[rr][c] = p;
                sum += p;
            }
            red[j][rr] = sum;
        }
        __syncthreads();
        if (t < 32) {
            float sm = 0.f;
#pragma unroll
            for (int jj = 0; jj < 8; jj++) sm += red[jj][t];
            rowl[t] = sm;
        }
        __syncthreads();
        // phase C: O = P @ V. thread (g=t>>5, d=t&31) does rows g+8k.
        {
            const int d = t & 31, g = t >> 5;
            float acc[4] = {0.f, 0.f, 0.f, 0.f};
            for (int c = 0; c < R; c += 4) {
                float v0 = Vs[c][d], v1 = Vs[c + 1][d];
                float v2 = Vs[c + 2][d], v3 = Vs[c + 3][d];
#pragma unroll
                for (int kk = 0; kk < 4; kk++) {
                    int r = g + kk * 8;
                    float a = fmaf(P[r][c + 0], v0, P[r][c + 1] * v1);
                    float b = fmaf(P[r][c + 2], v2, P[r][c + 3] * v3);
                    acc[kk] += a + b;
                }
            }
#pragma unroll
            for (int kk = 0; kk < 4; kk++) {
                int r = g + kk * 8;
                int rw = s * R + q0 + r;
                float val = acc[kk] / rowl[r];
                float gate = gb[(size_t)rw * E + h * D + d];
                ob[(size_t)rw * E + h * D + d] = val * gate;
            }
        }
    }
}

// ---------------------------------------------------------------------------
// K4: out = og @ wo + bo.  Same tiling as K2.
// ---------------------------------------------------------------------------
__global__ __launch_bounds__(256) void k_outproj(
    const float* __restrict__ ob, const float* __restrict__ wo,
    const float* __restrict__ bo, float* __restrict__ out)
{
    __shared__ float ot[32][260];
    const int t = threadIdx.x;
    const int row0 = blockIdx.x * 32;
#pragma unroll
    for (int i = 0; i < 8; i++) {
        int off = (i * 256 + t) * 4;
        int r = off >> 8, c = off & 255;
        *(float4*)&ot[r][c] = *(const float4*)(ob + (size_t)row0 * E + off);
    }
    __syncthreads();
    const int eg = t & 31, rg = t >> 5;
    const int e0 = eg * 8, r0 = rg * 4;
    float acc[4][8];
#pragma unroll
    for (int i = 0; i < 4; i++)
#pragma unroll
        for (int jj = 0; jj < 8; jj++) acc[i][jj] = 0.f;

    for (int c = 0; c < E; c += 4) {
#pragma unroll
        for (int cc = 0; cc < 4; cc++) {
            const float* wrow = wo + (size_t)(c + cc) * CIN + e0;
            float4 wlo = *(const float4*)wrow;
            float4 whi = *(const float4*)(wrow + 4);
            float wr[8] = {wlo.x, wlo.y, wlo.z, wlo.w,
                           whi.x, whi.y, whi.z, whi.w};
#pragma unroll
            for (int i = 0; i < 4; i++) {
                float a = ot[r0 + i][c + cc];
#pragma unroll
                for (int jj = 0; jj < 8; jj++)
                    acc[i][jj] = fmaf(a, wr[jj], acc[i][jj]);
            }
        }
    }
#pragma unroll
    for (int i = 0; i < 4; i++) {
        int rw = row0 + r0 + i;
        float* p = out + (size_t)rw * CIN + e0;
        float4 lo = {acc[i][0] + bo[e0 + 0], acc[i][1] + bo[e0 + 1],
                     acc[i][2] + bo[e0 + 2], acc[i][3] + bo[e0 + 3]};
        float4 hi = {acc[i][4] + bo[e0 + 4], acc[i][5] + bo[e0 + 5],
                     acc[i][6] + bo[e0 + 6], acc[i][7] + bo[e0 + 7]};
        *(float4*)p = lo;
        *(float4*)(p + 4) = hi;
    }
}

// ---------------------------------------------------------------------------
extern "C" void kernel_launch(void* const* d_in, const int* in_sizes, int n_in,
                              void* d_out, int out_size, void* d_ws, size_t ws_size,
                              hipStream_t stream)
{
    const float* m      = (const float*)d_in[0];
    const float* z      = (const float*)d_in[1];
    const float* mask   = (const float*)d_in[2];
    const float* ln_m_w = (const float*)d_in[3];
    const float* ln_m_b = (const float*)d_in[4];
    const float* ln_z_w = (const float*)d_in[5];
    const float* ln_z_b = (const float*)d_in[6];
    const float* w_pair = (const float*)d_in[7];
    const float* wq     = (const float*)d_in[8];
    const float* wk     = (const float*)d_in[9];
    const float* wv     = (const float*)d_in[10];
    const float* wg     = (const float*)d_in[11];
    const float* bg     = (const float*)d_in[12];
    const float* wo     = (const float*)d_in[13];
    const float* bo     = (const float*)d_in[14];
    float* out = (float*)d_out;

    float* ws = (float*)d_ws;
    const size_t PB_N  = (size_t)H * R * R;        // 1,179,648
    const size_t QKV_N = (size_t)S * H * R * D;    // 12,582,912
    float* pb = ws;
    float* qb = pb + PB_N;
    float* kb = qb + QKV_N;
    float* vb = kb + QKV_N;
    float* gb = vb + QKV_N;
    float* og = gb + QKV_N;

    k_pairbias<<<dim3(R * R / 4), dim3(256), 0, stream>>>(z, ln_z_w, ln_z_b, w_pair, pb);
    k_proj<<<dim3(S * R / 32), dim3(256), 0, stream>>>(m, ln_m_w, ln_m_b,
                                                       wq, wk, wv, wg, bg,
                                                       qb, kb, vb, gb);
    k_attn<<<dim3(S * H), dim3(256), 0, stream>>>(qb, kb, vb, gb, pb, mask, og);
    k_outproj<<<dim3(S * R / 32), dim3(256), 0, stream>>>(og, wo, bo, out);
}

// Round 2
// 906.336 us; speedup vs baseline: 2.0042x; 2.0042x over previous
//
#include <hip/hip_runtime.h>
#include <hip/hip_bf16.h>

#define S 128
#define R 384
#define CIN 256
#define H 8
#define D 32
#define CZ 128
#define E 256   // H*D

typedef __attribute__((ext_vector_type(8))) short short8;
typedef __attribute__((ext_vector_type(4))) short short4_;
typedef __attribute__((ext_vector_type(4))) float f32x4;

__device__ __forceinline__ short f2bs(float f) {
    __hip_bfloat16 h = __float2bfloat16(f);
    return *reinterpret_cast<short*>(&h);
}

// ---------------------------------------------------------------------------
// K1: pair bias  pb[h][q][k] = sum_c LN(z[q][k][:])[c] * w_pair[c][h]
// one wave (64 lanes) per (q,k) pair; block = 4 waves  (f32, unchanged)
// ---------------------------------------------------------------------------
__global__ __launch_bounds__(256) void k_pairbias(
    const float* __restrict__ z, const float* __restrict__ lnw,
    const float* __restrict__ lnb, const float* __restrict__ wp,
    float* __restrict__ pb)
{
    int wid  = blockIdx.x * 4 + (threadIdx.x >> 6);
    int lane = threadIdx.x & 63;
    int qi = wid / R;
    int ki = wid - qi * R;
    const float* zr = z + (size_t)wid * CZ;
    float z0 = zr[lane], z1 = zr[lane + 64];
    float s  = z0 + z1;
    float sq = z0 * z0 + z1 * z1;
#pragma unroll
    for (int off = 32; off >= 1; off >>= 1) {
        s  += __shfl_xor(s, off);
        sq += __shfl_xor(sq, off);
    }
    float mu   = s * (1.0f / CZ);
    float var  = sq * (1.0f / CZ) - mu * mu;
    float rstd = rsqrtf(var + 1e-5f);
    float zl0 = (z0 - mu) * rstd * lnw[lane]      + lnb[lane];
    float zl1 = (z1 - mu) * rstd * lnw[lane + 64] + lnb[lane + 64];
    const float* w0 = wp + lane * H;
    const float* w1 = wp + (lane + 64) * H;
    float ph[H];
#pragma unroll
    for (int h = 0; h < H; h++) ph[h] = zl0 * w0[h] + zl1 * w1[h];
#pragma unroll
    for (int off = 32; off >= 1; off >>= 1) {
#pragma unroll
        for (int h = 0; h < H; h++) ph[h] += __shfl_xor(ph[h], off);
    }
    if (lane == 0) {
#pragma unroll
        for (int h = 0; h < H; h++)
            pb[((size_t)h * R + qi) * R + ki] = ph[h];
    }
}

// ---------------------------------------------------------------------------
// K2: fused LN(m) + Q/K/V/G projections (f32 GEMM). Outputs:
//   q,k -> bf16 [s][h][res][d]   (q pre-scaled by D^-0.5)
//   v   -> bf16 TRANSPOSED [s][h][d][res]  (for PV B-fragments)
//   g   -> f32  [row][e] (sigmoided)
// ---------------------------------------------------------------------------
__global__ __launch_bounds__(256) void k_proj(
    const float* __restrict__ m, const float* __restrict__ lnw,
    const float* __restrict__ lnb,
    const float* __restrict__ wq, const float* __restrict__ wk,
    const float* __restrict__ wv, const float* __restrict__ wg,
    const float* __restrict__ bg,
    unsigned short* __restrict__ qb, unsigned short* __restrict__ kb,
    unsigned short* __restrict__ vtb, float* __restrict__ gb)
{
    __shared__ float mt[32][260];
    __shared__ float red[2][8][32];
    __shared__ float muv[32][2];
    const int t = threadIdx.x;
    const int row0 = blockIdx.x * 32;

#pragma unroll
    for (int i = 0; i < 8; i++) {
        int off = (i * 256 + t) * 4;
        int r = off >> 8, c = off & 255;
        *(float4*)&mt[r][c] = *(const float4*)(m + (size_t)(row0 + r) * CIN + c);
    }
    __syncthreads();
    {
        int r = t & 31, j = t >> 5;
        float s = 0.f, sq = 0.f;
#pragma unroll
        for (int i = 0; i < 32; i++) {
            float x = mt[r][j * 32 + i];
            s += x; sq += x * x;
        }
        red[0][j][r] = s; red[1][j][r] = sq;
    }
    __syncthreads();
    if (t < 32) {
        float s = 0.f, sq = 0.f;
#pragma unroll
        for (int j = 0; j < 8; j++) { s += red[0][j][t]; sq += red[1][j][t]; }
        float mu  = s * (1.0f / CIN);
        float var = sq * (1.0f / CIN) - mu * mu;
        muv[t][0] = mu;
        muv[t][1] = rsqrtf(var + 1e-5f);
    }
    __syncthreads();
    {
        float lw = lnw[t], lb = lnb[t];
#pragma unroll 4
        for (int r = 0; r < 32; r++) {
            float x = mt[r][t];
            mt[r][t] = (x - muv[r][0]) * muv[r][1] * lw + lb;
        }
    }
    __syncthreads();

    const int eg = t & 31, rg = t >> 5;
    const int e0 = eg * 8, r0 = rg * 4;
    const float* wmat[4] = {wq, wk, wv, wg};

    for (int mat = 0; mat < 4; mat++) {
        const float* __restrict__ w = wmat[mat];
        float acc[4][8];
#pragma unroll
        for (int i = 0; i < 4; i++)
#pragma unroll
            for (int jj = 0; jj < 8; jj++) acc[i][jj] = 0.f;

        for (int c = 0; c < CIN; c += 4) {
#pragma unroll
            for (int cc = 0; cc < 4; cc++) {
                const float* wrow = w + (size_t)(c + cc) * E + e0;
                float4 wlo = *(const float4*)wrow;
                float4 whi = *(const float4*)(wrow + 4);
                float wr[8] = {wlo.x, wlo.y, wlo.z, wlo.w,
                               whi.x, whi.y, whi.z, whi.w};
#pragma unroll
                for (int i = 0; i < 4; i++) {
                    float a = mt[r0 + i][c + cc];
#pragma unroll
                    for (int jj = 0; jj < 8; jj++)
                        acc[i][jj] = fmaf(a, wr[jj], acc[i][jj]);
                }
            }
        }
        const int hh = e0 >> 5, d0 = e0 & 31;
        if (mat == 0 || mat == 1) {
            unsigned short* dst = (mat == 0) ? qb : kb;
            float sc = (mat == 0) ? 0.17677669529663687f : 1.0f;
#pragma unroll
            for (int i = 0; i < 4; i++) {
                int rw = row0 + r0 + i;
                int ss = rw / R, res = rw - ss * R;
                unsigned short* p = dst + (((size_t)(ss * H + hh)) * R + res) * D + d0;
                short8 v;
#pragma unroll
                for (int jj = 0; jj < 8; jj++) v[jj] = f2bs(acc[i][jj] * sc);
                *(short8*)p = v;
            }
        } else if (mat == 2) {
            int rw0 = row0 + r0, ss = rw0 / R, res0 = rw0 - ss * R;
#pragma unroll
            for (int jj = 0; jj < 8; jj++) {
                unsigned short* p = vtb + (((size_t)(ss * H + hh)) * D + (d0 + jj)) * R + res0;
                short4_ v;
#pragma unroll
                for (int i = 0; i < 4; i++) v[i] = f2bs(acc[i][jj]);
                *(short4_*)p = v;
            }
        } else {
#pragma unroll
            for (int i = 0; i < 4; i++) {
                int rw = row0 + r0 + i;
#pragma unroll
                for (int jj = 0; jj < 8; jj++) {
                    float x = acc[i][jj] + bg[e0 + jj];
                    acc[i][jj] = 1.0f / (1.0f + __expf(-x));
                }
                float* p = gb + (size_t)rw * E + e0;
                float4 lo = {acc[i][0], acc[i][1], acc[i][2], acc[i][3]};
                float4 hi = {acc[i][4], acc[i][5], acc[i][6], acc[i][7]};
                *(float4*)p = lo;
                *(float4*)(p + 4) = hi;
            }
        }
    }
}

// ---------------------------------------------------------------------------
// K3: MFMA attention. One block per (s,h), 4 waves, no inter-wave barriers
// after staging. Wave w handles q-rows [w*96, w*96+96).
// QK^T: A=Q frag from global, B=K frag from LDS, C=bias (pb+mask).
// Softmax in C-layout registers (quad shuffles). P -> per-wave f32 LDS chunk
// -> re-read as A-frag, bf16-convert -> PV MFMA vs transposed V in LDS.
// LDS: Ks 30720 + Vt 25088 + Ps 25600 = 81408 B -> 2 blocks/CU.
// ---------------------------------------------------------------------------
__global__ __launch_bounds__(256, 2) void k_attn(
    const unsigned short* __restrict__ qb, const unsigned short* __restrict__ kb,
    const unsigned short* __restrict__ vtb, const float* __restrict__ gb,
    const float* __restrict__ pb, const float* __restrict__ mask,
    float* __restrict__ og)
{
    __shared__ unsigned short Ks[R][40];    // K [res][d], pitch 80 B
    __shared__ unsigned short Vt[D][392];   // V^T [d][res], pitch 784 B
    __shared__ float Ps[4][16][100];        // per-wave P chunk (96 cols + pad)
    const int t = threadIdx.x;
    const int s = blockIdx.x >> 3;
    const int h = blockIdx.x & 7;
    const size_t kvbase = (size_t)(s * H + h) * R * D;

    // stage K: 1536 chunks of 8 bf16
#pragma unroll
    for (int i = 0; i < 6; i++) {
        int idx = i * 256 + t;
        int res = idx >> 2, d = (idx & 3) * 8;
        *(short8*)&Ks[res][d] = *(const short8*)(kb + kvbase + (size_t)res * D + d);
    }
    // stage Vt
#pragma unroll
    for (int i = 0; i < 6; i++) {
        int idx = i * 256 + t;
        int d = idx / 48, j = idx - d * 48;
        *(short8*)&Vt[d][j * 8] = *(const short8*)(vtb + kvbase + (size_t)d * R + j * 8);
    }
    __syncthreads();

    const int w = t >> 6;
    const int lane = t & 63;
    const int ln = lane & 15;
    const int quad = lane >> 4;
    float (*Pw)[100] = Ps[w];

    // mask bias, cached per lane (col = tt*16 + ln)
    float mr[24];
#pragma unroll
    for (int tt = 0; tt < 24; tt++)
        mr[tt] = 1e9f * (mask[s * R + tt * 16 + ln] - 1.0f);

    for (int qt = 0; qt < 6; qt++) {
        const int q0 = w * 96 + qt * 16;
        // Q A-fragment: Q[q0+ln][quad*8 .. +7]
        short8 aq = *(const short8*)(qb + kvbase + (size_t)(q0 + ln) * D + quad * 8);
        const float* pbrow = pb + ((size_t)h * R + q0 + quad * 4) * R + ln;

        f32x4 acc[24];
#pragma unroll
        for (int tt = 0; tt < 24; tt++) {
            f32x4 c;
#pragma unroll
            for (int r = 0; r < 4; r++)
                c[r] = pbrow[(size_t)r * R + tt * 16] + mr[tt];
            short8 bk = *(const short8*)&Ks[tt * 16 + ln][quad * 8];
            acc[tt] = __builtin_amdgcn_mfma_f32_16x16x32_bf16(aq, bk, c, 0, 0, 0);
        }
        // softmax: row m = quad*4+r; cols live across 16 lanes of quad x 24 regs
        float l[4];
#pragma unroll
        for (int r = 0; r < 4; r++) {
            float mx = acc[0][r];
#pragma unroll
            for (int tt = 1; tt < 24; tt++) mx = fmaxf(mx, acc[tt][r]);
            mx = fmaxf(mx, __shfl_xor(mx, 1));
            mx = fmaxf(mx, __shfl_xor(mx, 2));
            mx = fmaxf(mx, __shfl_xor(mx, 4));
            mx = fmaxf(mx, __shfl_xor(mx, 8));
            float sum = 0.f;
#pragma unroll
            for (int tt = 0; tt < 24; tt++) {
                float p = __expf(acc[tt][r] - mx);
                acc[tt][r] = p;
                sum += p;
            }
            sum += __shfl_xor(sum, 1);
            sum += __shfl_xor(sum, 2);
            sum += __shfl_xor(sum, 4);
            sum += __shfl_xor(sum, 8);
            l[r] = sum;
        }
        // PV in 4 chunks of 96 k-cols (wave-private LDS roundtrip, no barrier)
        f32x4 o0 = {0.f, 0.f, 0.f, 0.f}, o1 = {0.f, 0.f, 0.f, 0.f};
        for (int cc = 0; cc < 4; cc++) {
#pragma unroll
            for (int tt6 = 0; tt6 < 6; tt6++) {
                int tt = cc * 6 + tt6;
#pragma unroll
                for (int r = 0; r < 4; r++)
                    Pw[quad * 4 + r][tt6 * 16 + ln] = acc[tt][r];
            }
#pragma unroll
            for (int kk = 0; kk < 3; kk++) {
                f32x4 plo = *(f32x4*)&Pw[ln][kk * 32 + quad * 8];
                f32x4 phi = *(f32x4*)&Pw[ln][kk * 32 + quad * 8 + 4];
                short8 ap;
#pragma unroll
                for (int j = 0; j < 4; j++) {
                    ap[j]     = f2bs(plo[j]);
                    ap[4 + j] = f2bs(phi[j]);
                }
                int kg = cc * 96 + kk * 32;
                short8 bv0 = *(const short8*)&Vt[ln][kg + quad * 8];
                short8 bv1 = *(const short8*)&Vt[16 + ln][kg + quad * 8];
                o0 = __builtin_amdgcn_mfma_f32_16x16x32_bf16(ap, bv0, o0, 0, 0, 0);
                o1 = __builtin_amdgcn_mfma_f32_16x16x32_bf16(ap, bv1, o1, 0, 0, 0);
            }
        }
        // epilogue: divide by l, gate, store f32
#pragma unroll
        for (int r = 0; r < 4; r++) {
            int mrow = quad * 4 + r;
            int rw = s * R + q0 + mrow;
            float invl = 1.0f / l[r];
            size_t base = (size_t)rw * E + h * D;
            float g0 = gb[base + ln];
            float g1 = gb[base + 16 + ln];
            og[base + ln]      = o0[r] * invl * g0;
            og[base + 16 + ln] = o1[r] * invl * g1;
        }
    }
}

// ---------------------------------------------------------------------------
// K4: out = og @ wo + bo.  (f32, unchanged)
// ---------------------------------------------------------------------------
__global__ __launch_bounds__(256) void k_outproj(
    const float* __restrict__ ob, const float* __restrict__ wo,
    const float* __restrict__ bo, float* __restrict__ out)
{
    __shared__ float ot[32][260];
    const int t = threadIdx.x;
    const int row0 = blockIdx.x * 32;
#pragma unroll
    for (int i = 0; i < 8; i++) {
        int off = (i * 256 + t) * 4;
        int r = off >> 8, c = off & 255;
        *(float4*)&ot[r][c] = *(const float4*)(ob + (size_t)row0 * E + off);
    }
    __syncthreads();
    const int eg = t & 31, rg = t >> 5;
    const int e0 = eg * 8, r0 = rg * 4;
    float acc[4][8];
#pragma unroll
    for (int i = 0; i < 4; i++)
#pragma unroll
        for (int jj = 0; jj < 8; jj++) acc[i][jj] = 0.f;

    for (int c = 0; c < E; c += 4) {
#pragma unroll
        for (int cc = 0; cc < 4; cc++) {
            const float* wrow = wo + (size_t)(c + cc) * CIN + e0;
            float4 wlo = *(const float4*)wrow;
            float4 whi = *(const float4*)(wrow + 4);
            float wr[8] = {wlo.x, wlo.y, wlo.z, wlo.w,
                           whi.x, whi.y, whi.z, whi.w};
#pragma unroll
            for (int i = 0; i < 4; i++) {
                float a = ot[r0 + i][c + cc];
#pragma unroll
                for (int jj = 0; jj < 8; jj++)
                    acc[i][jj] = fmaf(a, wr[jj], acc[i][jj]);
            }
        }
    }
#pragma unroll
    for (int i = 0; i < 4; i++) {
        int rw = row0 + r0 + i;
        float* p = out + (size_t)rw * CIN + e0;
        float4 lo = {acc[i][0] + bo[e0 + 0], acc[i][1] + bo[e0 + 1],
                     acc[i][2] + bo[e0 + 2], acc[i][3] + bo[e0 + 3]};
        float4 hi = {acc[i][4] + bo[e0 + 4], acc[i][5] + bo[e0 + 5],
                     acc[i][6] + bo[e0 + 6], acc[i][7] + bo[e0 + 7]};
        *(float4*)p = lo;
        *(float4*)(p + 4) = hi;
    }
}

// ---------------------------------------------------------------------------
extern "C" void kernel_launch(void* const* d_in, const int* in_sizes, int n_in,
                              void* d_out, int out_size, void* d_ws, size_t ws_size,
                              hipStream_t stream)
{
    const float* m      = (const float*)d_in[0];
    const float* z      = (const float*)d_in[1];
    const float* mask   = (const float*)d_in[2];
    const float* ln_m_w = (const float*)d_in[3];
    const float* ln_m_b = (const float*)d_in[4];
    const float* ln_z_w = (const float*)d_in[5];
    const float* ln_z_b = (const float*)d_in[6];
    const float* w_pair = (const float*)d_in[7];
    const float* wq     = (const float*)d_in[8];
    const float* wk     = (const float*)d_in[9];
    const float* wv     = (const float*)d_in[10];
    const float* wg     = (const float*)d_in[11];
    const float* bg     = (const float*)d_in[12];
    const float* wo     = (const float*)d_in[13];
    const float* bo     = (const float*)d_in[14];
    float* out = (float*)d_out;

    char* ws = (char*)d_ws;
    const size_t PB_B  = (size_t)H * R * R * 4;          // 4,718,592
    const size_t QKV_B = (size_t)S * H * R * D * 2;      // 25,165,824 (bf16)
    const size_t GB_B  = (size_t)S * R * E * 4;          // 50,331,648 (f32)
    float*          pbuf = (float*)ws;
    unsigned short* qb   = (unsigned short*)(ws + PB_B);
    unsigned short* kb   = (unsigned short*)(ws + PB_B + QKV_B);
    unsigned short* vtb  = (unsigned short*)(ws + PB_B + 2 * QKV_B);
    float*          gbuf = (float*)(ws + PB_B + 3 * QKV_B);
    float*          og   = (float*)(ws + PB_B + 3 * QKV_B + GB_B);

    k_pairbias<<<dim3(R * R / 4), dim3(256), 0, stream>>>(z, ln_z_w, ln_z_b, w_pair, pbuf);
    k_proj<<<dim3(S * R / 32), dim3(256), 0, stream>>>(m, ln_m_w, ln_m_b,
                                                       wq, wk, wv, wg, bg,
                                                       qb, kb, vtb, gbuf);
    k_attn<<<dim3(S * H), dim3(256), 0, stream>>>(qb, kb, vtb, gbuf, pbuf, mask, og);
    k_outproj<<<dim3(S * R / 32), dim3(256), 0, stream>>>(og, wo, bo, out);
}

// Round 3
// 525.481 us; speedup vs baseline: 3.4568x; 1.7248x over previous
//
#include <hip/hip_runtime.h>
#include <hip/hip_bf16.h>

#define S 128
#define R 384
#define CIN 256
#define H 8
#define D 32
#define CZ 128
#define E 256   // H*D

typedef __attribute__((ext_vector_type(8))) short short8;
typedef __attribute__((ext_vector_type(4))) short short4_;
typedef __attribute__((ext_vector_type(4))) float f32x4;
typedef __attribute__((ext_vector_type(4))) unsigned int u32x4;

union U8 { short8 s; unsigned int u[4]; };

__device__ __forceinline__ unsigned short f2bs_u(float f) {
    __hip_bfloat16 h = __float2bfloat16(f);
    return *reinterpret_cast<unsigned short*>(&h);
}
__device__ __forceinline__ short f2bs(float f) {
    __hip_bfloat16 h = __float2bfloat16(f);
    return *reinterpret_cast<short*>(&h);
}
__device__ __forceinline__ float bs2f(unsigned short u) {
    union { unsigned int i; float f; } c;
    c.i = ((unsigned int)u) << 16;
    return c.f;
}
// pack f32 -> (hi bf16 in low16, lo bf16 in high16)
__device__ __forceinline__ unsigned int packhl(float x) {
    unsigned short h = f2bs_u(x);
    float rem = x - bs2f(h);
    unsigned short l = f2bs_u(rem);
    return (unsigned int)h | ((unsigned int)l << 16);
}
// 4x4 transpose across 4 lanes (p = lane&3), regs x0..x3
__device__ __forceinline__ void xpose4(float& x0, float& x1, float& x2, float& x3, int p) {
    float tmp;
    if (p & 1) { tmp = x0; x0 = x1; x1 = tmp; tmp = x2; x2 = x3; x3 = tmp; }
    x1 = __shfl_xor(x1, 1); x3 = __shfl_xor(x3, 1);
    if (p & 1) { tmp = x0; x0 = x1; x1 = tmp; tmp = x2; x2 = x3; x3 = tmp; }
    if (p & 2) { tmp = x0; x0 = x2; x2 = tmp; tmp = x1; x1 = x3; x3 = tmp; }
    x2 = __shfl_xor(x2, 2); x3 = __shfl_xor(x3, 2);
    if (p & 2) { tmp = x0; x0 = x2; x2 = tmp; tmp = x1; x1 = x3; x3 = tmp; }
}

// ---------------------------------------------------------------------------
// K0: weight prep. Transpose to e-major and split into bf16 hi/lo.
// blocks 0..255: wq/wk/wv/wg -> wt[mat][e][c]; blocks 256..319: wo -> wot[cout][e]
// ---------------------------------------------------------------------------
__global__ __launch_bounds__(256) void k_prepw(
    const float* __restrict__ wq, const float* __restrict__ wk,
    const float* __restrict__ wv, const float* __restrict__ wg,
    const float* __restrict__ wo,
    unsigned short* __restrict__ wt_hi, unsigned short* __restrict__ wt_lo,
    unsigned short* __restrict__ wot_hi, unsigned short* __restrict__ wot_lo)
{
    __shared__ float tl[32][36];
    const int b = blockIdx.x, t = threadIdx.x;
    const int iswo = (b >= 256);
    const int bb = iswo ? (b - 256) : (b & 63);
    const int te = bb >> 3, tc = bb & 7;
    const int mat = b >> 6;
    const float* src = iswo ? wo : (mat == 0 ? wq : mat == 1 ? wk : mat == 2 ? wv : wg);
    unsigned short* dh = iswo ? wot_hi : wt_hi + (size_t)mat * 65536;
    unsigned short* dl = iswo ? wot_lo : wt_lo + (size_t)mat * 65536;

    const int r = t >> 3, c4 = (t & 7) * 4;
    float4 v = *(const float4*)(src + (size_t)(tc * 32 + r) * 256 + te * 32 + c4);
    tl[r][c4] = v.x; tl[r][c4 + 1] = v.y; tl[r][c4 + 2] = v.z; tl[r][c4 + 3] = v.w;
    __syncthreads();
    short4_ hv, lv;
#pragma unroll
    for (int j = 0; j < 4; j++) {
        float x = tl[c4 + j][r];
        unsigned short hb = f2bs_u(x);
        hv[j] = (short)hb;
        lv[j] = f2bs(x - bs2f(hb));
    }
    size_t o = (size_t)(te * 32 + r) * 256 + tc * 32 + c4;
    *(short4_*)(dh + o) = hv;
    *(short4_*)(dl + o) = lv;
}

// ---------------------------------------------------------------------------
// K1: pair bias (f32, unchanged)
// ---------------------------------------------------------------------------
__global__ __launch_bounds__(256) void k_pairbias(
    const float* __restrict__ z, const float* __restrict__ lnw,
    const float* __restrict__ lnb, const float* __restrict__ wp,
    float* __restrict__ pb)
{
    int wid  = blockIdx.x * 4 + (threadIdx.x >> 6);
    int lane = threadIdx.x & 63;
    int qi = wid / R;
    int ki = wid - qi * R;
    const float* zr = z + (size_t)wid * CZ;
    float z0 = zr[lane], z1 = zr[lane + 64];
    float s  = z0 + z1;
    float sq = z0 * z0 + z1 * z1;
#pragma unroll
    for (int off = 32; off >= 1; off >>= 1) {
        s  += __shfl_xor(s, off);
        sq += __shfl_xor(sq, off);
    }
    float mu   = s * (1.0f / CZ);
    float var  = sq * (1.0f / CZ) - mu * mu;
    float rstd = rsqrtf(var + 1e-5f);
    float zl0 = (z0 - mu) * rstd * lnw[lane]      + lnb[lane];
    float zl1 = (z1 - mu) * rstd * lnw[lane + 64] + lnb[lane + 64];
    const float* w0 = wp + lane * H;
    const float* w1 = wp + (lane + 64) * H;
    float ph[H];
#pragma unroll
    for (int h = 0; h < H; h++) ph[h] = zl0 * w0[h] + zl1 * w1[h];
#pragma unroll
    for (int off = 32; off >= 1; off >>= 1) {
#pragma unroll
        for (int h = 0; h < H; h++) ph[h] += __shfl_xor(ph[h], off);
    }
    if (lane == 0) {
#pragma unroll
        for (int h = 0; h < H; h++)
            pb[((size_t)h * R + qi) * R + ki] = ph[h];
    }
}

// ---------------------------------------------------------------------------
// K2: LN(m) + Q/K/V/G projections via split-bf16 MFMA (f32-quality).
// 64 rows/block, 4 waves; wave w = matrix w. A staged in LDS as packed
// (hi,lo) bf16 pairs in-place of f32. B hi/lo frags from global (L2-hot).
// ---------------------------------------------------------------------------
__global__ __launch_bounds__(256, 2) void k_proj(
    const float* __restrict__ m, const float* __restrict__ lnw,
    const float* __restrict__ lnb,
    const unsigned short* __restrict__ wt_hi, const unsigned short* __restrict__ wt_lo,
    const float* __restrict__ bg,
    unsigned short* __restrict__ qb, unsigned short* __restrict__ kb,
    unsigned short* __restrict__ vtb, float* __restrict__ gb)
{
    __shared__ unsigned int mtb[64][260];
    __shared__ float red[2][4][64];
    __shared__ float muv[64][2];
    const int t = threadIdx.x;
    const int row0 = blockIdx.x * 64;
    const int sblk = blockIdx.x / 6;
    const int res0 = (blockIdx.x % 6) * 64;

    // stage m 64x256 f32
#pragma unroll
    for (int i = 0; i < 16; i++) {
        int e4 = i * 256 + t;
        int r = e4 >> 6, c = (e4 & 63) * 4;
        f32x4 v = *(const f32x4*)(m + (size_t)(row0 + r) * CIN + c);
        *(f32x4*)&mtb[r][c] = v;
    }
    __syncthreads();
    // LN stats: 4 threads per row
    {
        int row = t & 63, j = t >> 6;
        float s = 0.f, sq = 0.f;
#pragma unroll
        for (int i = 0; i < 16; i++) {
            f32x4 v = *(const f32x4*)&mtb[row][j * 64 + i * 4];
#pragma unroll
            for (int q = 0; q < 4; q++) { s += v[q]; sq += v[q] * v[q]; }
        }
        red[0][j][row] = s; red[1][j][row] = sq;
    }
    __syncthreads();
    if (t < 64) {
        float s  = red[0][0][t] + red[0][1][t] + red[0][2][t] + red[0][3][t];
        float sq = red[1][0][t] + red[1][1][t] + red[1][2][t] + red[1][3][t];
        float mu  = s * (1.0f / CIN);
        float var = sq * (1.0f / CIN) - mu * mu;
        muv[t][0] = mu;
        muv[t][1] = rsqrtf(var + 1e-5f);
    }
    __syncthreads();
    // normalize + split-pack in place (thread t owns column t)
    {
        float lw = lnw[t], lb = lnb[t];
#pragma unroll 8
        for (int r = 0; r < 64; r++) {
            union { unsigned int i; float f; } c;
            c.i = mtb[r][t];
            float y = (c.f - muv[r][0]) * muv[r][1] * lw + lb;
            mtb[r][t] = packhl(y);
        }
    }
    __syncthreads();

    const int w = t >> 6, lane = t & 63, ln = lane & 15, quad = lane >> 4;
    const unsigned short* Bh = wt_hi + (size_t)w * 65536;
    const unsigned short* Bl = wt_lo + (size_t)w * 65536;

    for (int nc = 0; nc < 4; nc++) {
        const int nbase = nc * 64;
        f32x4 acc[4][4];
#pragma unroll
        for (int a = 0; a < 4; a++)
#pragma unroll
            for (int b = 0; b < 4; b++) acc[a][b] = (f32x4){0.f, 0.f, 0.f, 0.f};

        for (int kk = 0; kk < 8; kk++) {
            const int kcol = kk * 32 + quad * 8;
            short8 ah[4], al[4];
#pragma unroll
            for (int mt = 0; mt < 4; mt++) {
                const unsigned int* up = &mtb[mt * 16 + ln][kcol];
                u32x4 u0 = *(const u32x4*)up;
                u32x4 u1 = *(const u32x4*)(up + 4);
                U8 A, L;
                A.u[0] = (u0[0] & 0xffffu) | (u0[1] << 16);
                A.u[1] = (u0[2] & 0xffffu) | (u0[3] << 16);
                A.u[2] = (u1[0] & 0xffffu) | (u1[1] << 16);
                A.u[3] = (u1[2] & 0xffffu) | (u1[3] << 16);
                L.u[0] = (u0[0] >> 16) | (u0[1] & 0xffff0000u);
                L.u[1] = (u0[2] >> 16) | (u0[3] & 0xffff0000u);
                L.u[2] = (u1[0] >> 16) | (u1[1] & 0xffff0000u);
                L.u[3] = (u1[2] >> 16) | (u1[3] & 0xffff0000u);
                ah[mt] = A.s; al[mt] = L.s;
            }
#pragma unroll
            for (int nt = 0; nt < 4; nt++) {
                size_t boff = (size_t)(nbase + nt * 16 + ln) * 256 + kcol;
                short8 bh = *(const short8*)(Bh + boff);
                short8 bl = *(const short8*)(Bl + boff);
#pragma unroll
                for (int mt = 0; mt < 4; mt++) {
                    acc[mt][nt] = __builtin_amdgcn_mfma_f32_16x16x32_bf16(ah[mt], bh, acc[mt][nt], 0, 0, 0);
                    acc[mt][nt] = __builtin_amdgcn_mfma_f32_16x16x32_bf16(al[mt], bh, acc[mt][nt], 0, 0, 0);
                    acc[mt][nt] = __builtin_amdgcn_mfma_f32_16x16x32_bf16(ah[mt], bl, acc[mt][nt], 0, 0, 0);
                }
            }
        }
        // epilogue
        if (w == 2) {
            // V: C-layout is already res-contiguous per lane -> vt[h][d][res]
#pragma unroll
            for (int mt = 0; mt < 4; mt++) {
                int resg = res0 + mt * 16 + quad * 4;
#pragma unroll
                for (int nt = 0; nt < 4; nt++) {
                    int e = nbase + nt * 16 + ln;
                    int hh = e >> 5, d = e & 31;
                    f32x4 a = acc[mt][nt];
                    short4_ vv;
                    vv[0] = f2bs(a[0]); vv[1] = f2bs(a[1]);
                    vv[2] = f2bs(a[2]); vv[3] = f2bs(a[3]);
                    *(short4_*)(vtb + (((size_t)(sblk * H + hh)) * D + d) * R + resg) = vv;
                }
            }
        } else if (w == 3) {
            const int p = ln & 3;
#pragma unroll
            for (int mt = 0; mt < 4; mt++) {
                int rowg = row0 + mt * 16 + quad * 4 + p;
#pragma unroll
                for (int nt = 0; nt < 4; nt++) {
                    int e0 = nbase + nt * 16 + (ln & 12);
                    f32x4 a = acc[mt][nt];
                    float x0 = a[0], x1 = a[1], x2 = a[2], x3 = a[3];
                    xpose4(x0, x1, x2, x3, p);
                    float4 bgv = *(const float4*)(bg + e0);
                    f32x4 g;
                    g[0] = 1.0f / (1.0f + __expf(-(x0 + bgv.x)));
                    g[1] = 1.0f / (1.0f + __expf(-(x1 + bgv.y)));
                    g[2] = 1.0f / (1.0f + __expf(-(x2 + bgv.z)));
                    g[3] = 1.0f / (1.0f + __expf(-(x3 + bgv.w)));
                    *(f32x4*)(gb + (size_t)rowg * E + e0) = g;
                }
            }
        } else {
            const float sc = (w == 0) ? 0.17677669529663687f : 1.0f;
            unsigned short* dst = (w == 0) ? qb : kb;
            const int p = ln & 3;
#pragma unroll
            for (int mt = 0; mt < 4; mt++) {
                int resg = res0 + mt * 16 + quad * 4 + p;
#pragma unroll
                for (int nt = 0; nt < 4; nt++) {
                    int e0 = nbase + nt * 16 + (ln & 12);
                    f32x4 a = acc[mt][nt];
                    float x0 = a[0] * sc, x1 = a[1] * sc, x2 = a[2] * sc, x3 = a[3] * sc;
                    xpose4(x0, x1, x2, x3, p);
                    int hh = e0 >> 5, d0 = e0 & 31;
                    short4_ vv;
                    vv[0] = f2bs(x0); vv[1] = f2bs(x1); vv[2] = f2bs(x2); vv[3] = f2bs(x3);
                    *(short4_*)(dst + (((size_t)(sblk * H + hh)) * R + resg) * D + d0) = vv;
                }
            }
        }
    }
}

// ---------------------------------------------------------------------------
// K3: MFMA attention (unchanged from round 2)
// ---------------------------------------------------------------------------
__global__ __launch_bounds__(256, 2) void k_attn(
    const unsigned short* __restrict__ qb, const unsigned short* __restrict__ kb,
    const unsigned short* __restrict__ vtb, const float* __restrict__ gb,
    const float* __restrict__ pb, const float* __restrict__ mask,
    float* __restrict__ og)
{
    __shared__ unsigned short Ks[R][40];
    __shared__ unsigned short Vt[D][392];
    __shared__ float Ps[4][16][100];
    const int t = threadIdx.x;
    const int s = blockIdx.x >> 3;
    const int h = blockIdx.x & 7;
    const size_t kvbase = (size_t)(s * H + h) * R * D;

#pragma unroll
    for (int i = 0; i < 6; i++) {
        int idx = i * 256 + t;
        int res = idx >> 2, d = (idx & 3) * 8;
        *(short8*)&Ks[res][d] = *(const short8*)(kb + kvbase + (size_t)res * D + d);
    }
#pragma unroll
    for (int i = 0; i < 6; i++) {
        int idx = i * 256 + t;
        int d = idx / 48, j = idx - d * 48;
        *(short8*)&Vt[d][j * 8] = *(const short8*)(vtb + kvbase + (size_t)d * R + j * 8);
    }
    __syncthreads();

    const int w = t >> 6;
    const int lane = t & 63;
    const int ln = lane & 15;
    const int quad = lane >> 4;
    float (*Pw)[100] = Ps[w];

    float mr[24];
#pragma unroll
    for (int tt = 0; tt < 24; tt++)
        mr[tt] = 1e9f * (mask[s * R + tt * 16 + ln] - 1.0f);

    for (int qt = 0; qt < 6; qt++) {
        const int q0 = w * 96 + qt * 16;
        short8 aq = *(const short8*)(qb + kvbase + (size_t)(q0 + ln) * D + quad * 8);
        const float* pbrow = pb + ((size_t)h * R + q0 + quad * 4) * R + ln;

        f32x4 acc[24];
#pragma unroll
        for (int tt = 0; tt < 24; tt++) {
            f32x4 c;
#pragma unroll
            for (int r = 0; r < 4; r++)
                c[r] = pbrow[(size_t)r * R + tt * 16] + mr[tt];
            short8 bk = *(const short8*)&Ks[tt * 16 + ln][quad * 8];
            acc[tt] = __builtin_amdgcn_mfma_f32_16x16x32_bf16(aq, bk, c, 0, 0, 0);
        }
        float l[4];
#pragma unroll
        for (int r = 0; r < 4; r++) {
            float mx = acc[0][r];
#pragma unroll
            for (int tt = 1; tt < 24; tt++) mx = fmaxf(mx, acc[tt][r]);
            mx = fmaxf(mx, __shfl_xor(mx, 1));
            mx = fmaxf(mx, __shfl_xor(mx, 2));
            mx = fmaxf(mx, __shfl_xor(mx, 4));
            mx = fmaxf(mx, __shfl_xor(mx, 8));
            float sum = 0.f;
#pragma unroll
            for (int tt = 0; tt < 24; tt++) {
                float p = __expf(acc[tt][r] - mx);
                acc[tt][r] = p;
                sum += p;
            }
            sum += __shfl_xor(sum, 1);
            sum += __shfl_xor(sum, 2);
            sum += __shfl_xor(sum, 4);
            sum += __shfl_xor(sum, 8);
            l[r] = sum;
        }
        f32x4 o0 = {0.f, 0.f, 0.f, 0.f}, o1 = {0.f, 0.f, 0.f, 0.f};
        for (int cc = 0; cc < 4; cc++) {
#pragma unroll
            for (int tt6 = 0; tt6 < 6; tt6++) {
                int tt = cc * 6 + tt6;
#pragma unroll
                for (int r = 0; r < 4; r++)
                    Pw[quad * 4 + r][tt6 * 16 + ln] = acc[tt][r];
            }
#pragma unroll
            for (int kk = 0; kk < 3; kk++) {
                f32x4 plo = *(f32x4*)&Pw[ln][kk * 32 + quad * 8];
                f32x4 phi = *(f32x4*)&Pw[ln][kk * 32 + quad * 8 + 4];
                short8 ap;
#pragma unroll
                for (int j = 0; j < 4; j++) {
                    ap[j]     = f2bs(plo[j]);
                    ap[4 + j] = f2bs(phi[j]);
                }
                int kg = cc * 96 + kk * 32;
                short8 bv0 = *(const short8*)&Vt[ln][kg + quad * 8];
                short8 bv1 = *(const short8*)&Vt[16 + ln][kg + quad * 8];
                o0 = __builtin_amdgcn_mfma_f32_16x16x32_bf16(ap, bv0, o0, 0, 0, 0);
                o1 = __builtin_amdgcn_mfma_f32_16x16x32_bf16(ap, bv1, o1, 0, 0, 0);
            }
        }
#pragma unroll
        for (int r = 0; r < 4; r++) {
            int mrow = quad * 4 + r;
            int rw = s * R + q0 + mrow;
            float invl = 1.0f / l[r];
            size_t base = (size_t)rw * E + h * D;
            float g0 = gb[base + ln];
            float g1 = gb[base + 16 + ln];
            og[base + ln]      = o0[r] * invl * g0;
            og[base + 16 + ln] = o1[r] * invl * g1;
        }
    }
}

// ---------------------------------------------------------------------------
// K4: out = og @ wo + bo via split-bf16 MFMA.
// 64 rows/block, 4 waves; wave w = col-chunk w (64 cols).
// ---------------------------------------------------------------------------
__global__ __launch_bounds__(256, 2) void k_outproj(
    const float* __restrict__ og, const unsigned short* __restrict__ wot_hi,
    const unsigned short* __restrict__ wot_lo, const float* __restrict__ bo,
    float* __restrict__ out)
{
    __shared__ unsigned int otb[64][260];
    const int t = threadIdx.x;
    const int row0 = blockIdx.x * 64;
#pragma unroll
    for (int i = 0; i < 16; i++) {
        int e4 = i * 256 + t;
        int r = e4 >> 6, c = (e4 & 63) * 4;
        f32x4 v = *(const f32x4*)(og + (size_t)(row0 + r) * E + c);
        u32x4 pk;
        pk[0] = packhl(v[0]); pk[1] = packhl(v[1]);
        pk[2] = packhl(v[2]); pk[3] = packhl(v[3]);
        *(u32x4*)&otb[r][c] = pk;
    }
    __syncthreads();

    const int w = t >> 6, lane = t & 63, ln = lane & 15, quad = lane >> 4;
    const int nbase = w * 64;
    f32x4 acc[4][4];
#pragma unroll
    for (int a = 0; a < 4; a++)
#pragma unroll
        for (int b = 0; b < 4; b++) acc[a][b] = (f32x4){0.f, 0.f, 0.f, 0.f};

    for (int kk = 0; kk < 8; kk++) {
        const int kcol = kk * 32 + quad * 8;
        short8 ah[4], al[4];
#pragma unroll
        for (int mt = 0; mt < 4; mt++) {
            const unsigned int* up = &otb[mt * 16 + ln][kcol];
            u32x4 u0 = *(const u32x4*)up;
            u32x4 u1 = *(const u32x4*)(up + 4);
            U8 A, L;
            A.u[0] = (u0[0] & 0xffffu) | (u0[1] << 16);
            A.u[1] = (u0[2] & 0xffffu) | (u0[3] << 16);
            A.u[2] = (u1[0] & 0xffffu) | (u1[1] << 16);
            A.u[3] = (u1[2] & 0xffffu) | (u1[3] << 16);
            L.u[0] = (u0[0] >> 16) | (u0[1] & 0xffff0000u);
            L.u[1] = (u0[2] >> 16) | (u0[3] & 0xffff0000u);
            L.u[2] = (u1[0] >> 16) | (u1[1] & 0xffff0000u);
            L.u[3] = (u1[2] >> 16) | (u1[3] & 0xffff0000u);
            ah[mt] = A.s; al[mt] = L.s;
        }
#pragma unroll
        for (int nt = 0; nt < 4; nt++) {
            size_t boff = (size_t)(nbase + nt * 16 + ln) * 256 + kcol;
            short8 bh = *(const short8*)(wot_hi + boff);
            short8 bl = *(const short8*)(wot_lo + boff);
#pragma unroll
            for (int mt = 0; mt < 4; mt++) {
                acc[mt][nt] = __builtin_amdgcn_mfma_f32_16x16x32_bf16(ah[mt], bh, acc[mt][nt], 0, 0, 0);
                acc[mt][nt] = __builtin_amdgcn_mfma_f32_16x16x32_bf16(al[mt], bh, acc[mt][nt], 0, 0, 0);
                acc[mt][nt] = __builtin_amdgcn_mfma_f32_16x16x32_bf16(ah[mt], bl, acc[mt][nt], 0, 0, 0);
            }
        }
    }
    const int p = ln & 3;
#pragma unroll
    for (int mt = 0; mt < 4; mt++) {
        int rowg = row0 + mt * 16 + quad * 4 + p;
#pragma unroll
        for (int nt = 0; nt < 4; nt++) {
            int c0 = nbase + nt * 16 + (ln & 12);
            f32x4 a = acc[mt][nt];
            float x0 = a[0], x1 = a[1], x2 = a[2], x3 = a[3];
            xpose4(x0, x1, x2, x3, p);
            float4 bov = *(const float4*)(bo + c0);
            f32x4 o;
            o[0] = x0 + bov.x; o[1] = x1 + bov.y;
            o[2] = x2 + bov.z; o[3] = x3 + bov.w;
            *(f32x4*)(out + (size_t)rowg * CIN + c0) = o;
        }
    }
}

// ---------------------------------------------------------------------------
extern "C" void kernel_launch(void* const* d_in, const int* in_sizes, int n_in,
                              void* d_out, int out_size, void* d_ws, size_t ws_size,
                              hipStream_t stream)
{
    const float* m      = (const float*)d_in[0];
    const float* z      = (const float*)d_in[1];
    const float* mask   = (const float*)d_in[2];
    const float* ln_m_w = (const float*)d_in[3];
    const float* ln_m_b = (const float*)d_in[4];
    const float* ln_z_w = (const float*)d_in[5];
    const float* ln_z_b = (const float*)d_in[6];
    const float* w_pair = (const float*)d_in[7];
    const float* wq     = (const float*)d_in[8];
    const float* wk     = (const float*)d_in[9];
    const float* wv     = (const float*)d_in[10];
    const float* wg     = (const float*)d_in[11];
    const float* bg     = (const float*)d_in[12];
    const float* wo     = (const float*)d_in[13];
    const float* bo     = (const float*)d_in[14];
    float* out = (float*)d_out;

    char* ws = (char*)d_ws;
    float*          pbuf   = (float*)ws;              ws += 4718592;
    unsigned short* qb     = (unsigned short*)ws;     ws += 25165824;
    unsigned short* kb     = (unsigned short*)ws;     ws += 25165824;
    unsigned short* vtb    = (unsigned short*)ws;     ws += 25165824;
    float*          gbuf   = (float*)ws;              ws += 50331648;
    float*          ogb    = (float*)ws;              ws += 50331648;
    unsigned short* wt_hi  = (unsigned short*)ws;     ws += 524288;
    unsigned short* wt_lo  = (unsigned short*)ws;     ws += 524288;
    unsigned short* wot_hi = (unsigned short*)ws;     ws += 131072;
    unsigned short* wot_lo = (unsigned short*)ws;     ws += 131072;

    k_prepw<<<dim3(320), dim3(256), 0, stream>>>(wq, wk, wv, wg, wo,
                                                 wt_hi, wt_lo, wot_hi, wot_lo);
    k_pairbias<<<dim3(R * R / 4), dim3(256), 0, stream>>>(z, ln_z_w, ln_z_b, w_pair, pbuf);
    k_proj<<<dim3(768), dim3(256), 0, stream>>>(m, ln_m_w, ln_m_b,
                                                wt_hi, wt_lo, bg, qb, kb, vtb, gbuf);
    k_attn<<<dim3(S * H), dim3(256), 0, stream>>>(qb, kb, vtb, gbuf, pbuf, mask, ogb);
    k_outproj<<<dim3(768), dim3(256), 0, stream>>>(ogb, wot_hi, wot_lo, bo, out);
}

// Round 4
// 496.584 us; speedup vs baseline: 3.6580x; 1.0582x over previous
//
#include <hip/hip_runtime.h>
#include <hip/hip_bf16.h>

#define S 128
#define R 384
#define CIN 256
#define H 8
#define D 32
#define CZ 128
#define E 256   // H*D

typedef __attribute__((ext_vector_type(8))) short short8;
typedef __attribute__((ext_vector_type(4))) short short4_;
typedef __attribute__((ext_vector_type(4))) float f32x4;
typedef __attribute__((ext_vector_type(4))) unsigned int u32x4;

union U8 { short8 s; unsigned int u[4]; };

__device__ __forceinline__ unsigned short f2bs_u(float f) {
    __hip_bfloat16 h = __float2bfloat16(f);
    return *reinterpret_cast<unsigned short*>(&h);
}
__device__ __forceinline__ short f2bs(float f) {
    __hip_bfloat16 h = __float2bfloat16(f);
    return *reinterpret_cast<short*>(&h);
}
__device__ __forceinline__ float bs2f(unsigned short u) {
    union { unsigned int i; float f; } c;
    c.i = ((unsigned int)u) << 16;
    return c.f;
}
// pack f32 -> (hi bf16 in low16, lo bf16 in high16)
__device__ __forceinline__ unsigned int packhl(float x) {
    unsigned short h = f2bs_u(x);
    float rem = x - bs2f(h);
    unsigned short l = f2bs_u(rem);
    return (unsigned int)h | ((unsigned int)l << 16);
}
// 4x4 transpose across 4 lanes (p = lane&3), regs x0..x3
__device__ __forceinline__ void xpose4(float& x0, float& x1, float& x2, float& x3, int p) {
    float tmp;
    if (p & 1) { tmp = x0; x0 = x1; x1 = tmp; tmp = x2; x2 = x3; x3 = tmp; }
    x1 = __shfl_xor(x1, 1); x3 = __shfl_xor(x3, 1);
    if (p & 1) { tmp = x0; x0 = x1; x1 = tmp; tmp = x2; x2 = x3; x3 = tmp; }
    if (p & 2) { tmp = x0; x0 = x2; x2 = tmp; tmp = x1; x1 = x3; x3 = tmp; }
    x2 = __shfl_xor(x2, 2); x3 = __shfl_xor(x3, 2);
    if (p & 2) { tmp = x0; x0 = x2; x2 = tmp; tmp = x1; x1 = x3; x3 = tmp; }
}

// ---------------------------------------------------------------------------
// K0: weight prep. Transpose to e-major and split into bf16 hi/lo.
// blocks 0..255: wq/wk/wv/wg -> wt[mat][e][c]; blocks 256..319: wo -> wot[cout][e]
// ---------------------------------------------------------------------------
__global__ __launch_bounds__(256) void k_prepw(
    const float* __restrict__ wq, const float* __restrict__ wk,
    const float* __restrict__ wv, const float* __restrict__ wg,
    const float* __restrict__ wo,
    unsigned short* __restrict__ wt_hi, unsigned short* __restrict__ wt_lo,
    unsigned short* __restrict__ wot_hi, unsigned short* __restrict__ wot_lo)
{
    __shared__ float tl[32][36];
    const int b = blockIdx.x, t = threadIdx.x;
    const int iswo = (b >= 256);
    const int bb = iswo ? (b - 256) : (b & 63);
    const int te = bb >> 3, tc = bb & 7;
    const int mat = b >> 6;
    const float* src = iswo ? wo : (mat == 0 ? wq : mat == 1 ? wk : mat == 2 ? wv : wg);
    unsigned short* dh = iswo ? wot_hi : wt_hi + (size_t)mat * 65536;
    unsigned short* dl = iswo ? wot_lo : wt_lo + (size_t)mat * 65536;

    const int r = t >> 3, c4 = (t & 7) * 4;
    float4 v = *(const float4*)(src + (size_t)(tc * 32 + r) * 256 + te * 32 + c4);
    tl[r][c4] = v.x; tl[r][c4 + 1] = v.y; tl[r][c4 + 2] = v.z; tl[r][c4 + 3] = v.w;
    __syncthreads();
    short4_ hv, lv;
#pragma unroll
    for (int j = 0; j < 4; j++) {
        float x = tl[c4 + j][r];
        unsigned short hb = f2bs_u(x);
        hv[j] = (short)hb;
        lv[j] = f2bs(x - bs2f(hb));
    }
    size_t o = (size_t)(te * 32 + r) * 256 + tc * 32 + c4;
    *(short4_*)(dh + o) = hv;
    *(short4_*)(dl + o) = lv;
}

// ---------------------------------------------------------------------------
// K1: pair bias (f32, unchanged)
// ---------------------------------------------------------------------------
__global__ __launch_bounds__(256) void k_pairbias(
    const float* __restrict__ z, const float* __restrict__ lnw,
    const float* __restrict__ lnb, const float* __restrict__ wp,
    float* __restrict__ pb)
{
    int wid  = blockIdx.x * 4 + (threadIdx.x >> 6);
    int lane = threadIdx.x & 63;
    int qi = wid / R;
    int ki = wid - qi * R;
    const float* zr = z + (size_t)wid * CZ;
    float z0 = zr[lane], z1 = zr[lane + 64];
    float s  = z0 + z1;
    float sq = z0 * z0 + z1 * z1;
#pragma unroll
    for (int off = 32; off >= 1; off >>= 1) {
        s  += __shfl_xor(s, off);
        sq += __shfl_xor(sq, off);
    }
    float mu   = s * (1.0f / CZ);
    float var  = sq * (1.0f / CZ) - mu * mu;
    float rstd = rsqrtf(var + 1e-5f);
    float zl0 = (z0 - mu) * rstd * lnw[lane]      + lnb[lane];
    float zl1 = (z1 - mu) * rstd * lnw[lane + 64] + lnb[lane + 64];
    const float* w0 = wp + lane * H;
    const float* w1 = wp + (lane + 64) * H;
    float ph[H];
#pragma unroll
    for (int h = 0; h < H; h++) ph[h] = zl0 * w0[h] + zl1 * w1[h];
#pragma unroll
    for (int off = 32; off >= 1; off >>= 1) {
#pragma unroll
        for (int h = 0; h < H; h++) ph[h] += __shfl_xor(ph[h], off);
    }
    if (lane == 0) {
#pragma unroll
        for (int h = 0; h < H; h++)
            pb[((size_t)h * R + qi) * R + ki] = ph[h];
    }
}

// ---------------------------------------------------------------------------
// K2 v3: LN(m) + Q/K/V/G projections. A = plain bf16 plane in LDS
// (fragment-ready, no bitops), B = weight hi/lo from global (L2-hot),
// 2 MFMAs per tile (A*Bh + A*Bl). 64 rows/block, wave w = matrix w.
// LDS ~34.4 KB -> 3 blocks/CU.
// ---------------------------------------------------------------------------
__global__ __launch_bounds__(256, 3) void k_proj(
    const float* __restrict__ m, const float* __restrict__ lnw,
    const float* __restrict__ lnb,
    const unsigned short* __restrict__ wt_hi, const unsigned short* __restrict__ wt_lo,
    const float* __restrict__ bg,
    unsigned short* __restrict__ qb, unsigned short* __restrict__ kb,
    unsigned short* __restrict__ vtb, unsigned short* __restrict__ gb)
{
    __shared__ unsigned short Ah[64][264];
    __shared__ float muv[64][2];
    const int t = threadIdx.x;
    const int row0 = blockIdx.x * 64;
    const int sblk = blockIdx.x / 6;
    const int res0 = (blockIdx.x % 6) * 64;

    // pass 1: LN stats, 2 threads per row (partners adjacent in wave)
    if (t < 128) {
        int r = t >> 1, half = t & 1;
        const float* mr = m + (size_t)(row0 + r) * CIN + half * 128;
        float s = 0.f, sq = 0.f;
#pragma unroll
        for (int i = 0; i < 32; i++) {
            f32x4 v = *(const f32x4*)(mr + i * 4);
#pragma unroll
            for (int q = 0; q < 4; q++) { s += v[q]; sq += v[q] * v[q]; }
        }
        s  += __shfl_xor(s, 1);
        sq += __shfl_xor(sq, 1);
        if (half == 0) {
            float mu  = s * (1.0f / CIN);
            float var = sq * (1.0f / CIN) - mu * mu;
            muv[r][0] = mu;
            muv[r][1] = rsqrtf(var + 1e-5f);
        }
    }
    __syncthreads();
    // pass 2: normalize + bf16 -> LDS plane (tile is L2-hot from pass 1)
#pragma unroll
    for (int i = 0; i < 16; i++) {
        int idx = i * 256 + t;
        int r = idx >> 6, c4 = (idx & 63) * 4;
        f32x4 v = *(const f32x4*)(m + (size_t)(row0 + r) * CIN + c4);
        float4 lw = *(const float4*)(lnw + c4);
        float4 lb = *(const float4*)(lnb + c4);
        float mu = muv[r][0], rs = muv[r][1];
        short4_ o;
        o[0] = f2bs((v[0] - mu) * rs * lw.x + lb.x);
        o[1] = f2bs((v[1] - mu) * rs * lw.y + lb.y);
        o[2] = f2bs((v[2] - mu) * rs * lw.z + lb.z);
        o[3] = f2bs((v[3] - mu) * rs * lw.w + lb.w);
        *(short4_*)&Ah[r][c4] = o;
    }
    __syncthreads();

    const int w = t >> 6, lane = t & 63, ln = lane & 15, quad = lane >> 4;
    const unsigned short* Bh = wt_hi + (size_t)w * 65536;
    const unsigned short* Bl = wt_lo + (size_t)w * 65536;

    for (int nc = 0; nc < 4; nc++) {
        const int nbase = nc * 64;
        f32x4 acc[4][4];
#pragma unroll
        for (int a = 0; a < 4; a++)
#pragma unroll
            for (int b = 0; b < 4; b++) acc[a][b] = (f32x4){0.f, 0.f, 0.f, 0.f};

#pragma unroll 2
        for (int kk = 0; kk < 8; kk++) {
            const int kcol = kk * 32 + quad * 8;
            short8 ah[4];
#pragma unroll
            for (int mt = 0; mt < 4; mt++)
                ah[mt] = *(const short8*)&Ah[mt * 16 + ln][kcol];
#pragma unroll
            for (int nt = 0; nt < 4; nt++) {
                size_t boff = (size_t)(nbase + nt * 16 + ln) * 256 + kcol;
                short8 bh = *(const short8*)(Bh + boff);
                short8 bl = *(const short8*)(Bl + boff);
#pragma unroll
                for (int mt = 0; mt < 4; mt++) {
                    acc[mt][nt] = __builtin_amdgcn_mfma_f32_16x16x32_bf16(ah[mt], bh, acc[mt][nt], 0, 0, 0);
                    acc[mt][nt] = __builtin_amdgcn_mfma_f32_16x16x32_bf16(ah[mt], bl, acc[mt][nt], 0, 0, 0);
                }
            }
        }
        // epilogue
        if (w == 2) {
            // V: C-layout is res-contiguous per lane -> vt[h][d][res]
#pragma unroll
            for (int mt = 0; mt < 4; mt++) {
                int resg = res0 + mt * 16 + quad * 4;
#pragma unroll
                for (int nt = 0; nt < 4; nt++) {
                    int e = nbase + nt * 16 + ln;
                    int hh = e >> 5, d = e & 31;
                    f32x4 a = acc[mt][nt];
                    short4_ vv;
                    vv[0] = f2bs(a[0]); vv[1] = f2bs(a[1]);
                    vv[2] = f2bs(a[2]); vv[3] = f2bs(a[3]);
                    *(short4_*)(vtb + (((size_t)(sblk * H + hh)) * D + d) * R + resg) = vv;
                }
            }
        } else if (w == 3) {
            const int p = ln & 3;
#pragma unroll
            for (int mt = 0; mt < 4; mt++) {
                int rowg = row0 + mt * 16 + quad * 4 + p;
#pragma unroll
                for (int nt = 0; nt < 4; nt++) {
                    int e0 = nbase + nt * 16 + (ln & 12);
                    f32x4 a = acc[mt][nt];
                    float x0 = a[0], x1 = a[1], x2 = a[2], x3 = a[3];
                    xpose4(x0, x1, x2, x3, p);
                    float4 bgv = *(const float4*)(bg + e0);
                    short4_ gv;
                    gv[0] = f2bs(1.0f / (1.0f + __expf(-(x0 + bgv.x))));
                    gv[1] = f2bs(1.0f / (1.0f + __expf(-(x1 + bgv.y))));
                    gv[2] = f2bs(1.0f / (1.0f + __expf(-(x2 + bgv.z))));
                    gv[3] = f2bs(1.0f / (1.0f + __expf(-(x3 + bgv.w))));
                    *(short4_*)(gb + (size_t)rowg * E + e0) = gv;
                }
            }
        } else {
            const float sc = (w == 0) ? 0.17677669529663687f : 1.0f;
            unsigned short* dst = (w == 0) ? qb : kb;
            const int p = ln & 3;
#pragma unroll
            for (int mt = 0; mt < 4; mt++) {
                int resg = res0 + mt * 16 + quad * 4 + p;
#pragma unroll
                for (int nt = 0; nt < 4; nt++) {
                    int e0 = nbase + nt * 16 + (ln & 12);
                    f32x4 a = acc[mt][nt];
                    float x0 = a[0] * sc, x1 = a[1] * sc, x2 = a[2] * sc, x3 = a[3] * sc;
                    xpose4(x0, x1, x2, x3, p);
                    int hh = e0 >> 5, d0 = e0 & 31;
                    short4_ vv;
                    vv[0] = f2bs(x0); vv[1] = f2bs(x1); vv[2] = f2bs(x2); vv[3] = f2bs(x3);
                    *(short4_*)(dst + (((size_t)(sblk * H + hh)) * R + resg) * D + d0) = vv;
                }
            }
        }
    }
}

// ---------------------------------------------------------------------------
// K3: MFMA attention (g now bf16; otherwise unchanged)
// ---------------------------------------------------------------------------
__global__ __launch_bounds__(256, 2) void k_attn(
    const unsigned short* __restrict__ qb, const unsigned short* __restrict__ kb,
    const unsigned short* __restrict__ vtb, const unsigned short* __restrict__ gb,
    const float* __restrict__ pb, const float* __restrict__ mask,
    float* __restrict__ og)
{
    __shared__ unsigned short Ks[R][40];
    __shared__ unsigned short Vt[D][392];
    __shared__ float Ps[4][16][100];
    const int t = threadIdx.x;
    const int s = blockIdx.x >> 3;
    const int h = blockIdx.x & 7;
    const size_t kvbase = (size_t)(s * H + h) * R * D;

#pragma unroll
    for (int i = 0; i < 6; i++) {
        int idx = i * 256 + t;
        int res = idx >> 2, d = (idx & 3) * 8;
        *(short8*)&Ks[res][d] = *(const short8*)(kb + kvbase + (size_t)res * D + d);
    }
#pragma unroll
    for (int i = 0; i < 6; i++) {
        int idx = i * 256 + t;
        int d = idx / 48, j = idx - d * 48;
        *(short8*)&Vt[d][j * 8] = *(const short8*)(vtb + kvbase + (size_t)d * R + j * 8);
    }
    __syncthreads();

    const int w = t >> 6;
    const int lane = t & 63;
    const int ln = lane & 15;
    const int quad = lane >> 4;
    float (*Pw)[100] = Ps[w];

    float mr[24];
#pragma unroll
    for (int tt = 0; tt < 24; tt++)
        mr[tt] = 1e9f * (mask[s * R + tt * 16 + ln] - 1.0f);

    for (int qt = 0; qt < 6; qt++) {
        const int q0 = w * 96 + qt * 16;
        short8 aq = *(const short8*)(qb + kvbase + (size_t)(q0 + ln) * D + quad * 8);
        const float* pbrow = pb + ((size_t)h * R + q0 + quad * 4) * R + ln;

        f32x4 acc[24];
#pragma unroll
        for (int tt = 0; tt < 24; tt++) {
            f32x4 c;
#pragma unroll
            for (int r = 0; r < 4; r++)
                c[r] = pbrow[(size_t)r * R + tt * 16] + mr[tt];
            short8 bk = *(const short8*)&Ks[tt * 16 + ln][quad * 8];
            acc[tt] = __builtin_amdgcn_mfma_f32_16x16x32_bf16(aq, bk, c, 0, 0, 0);
        }
        float l[4];
#pragma unroll
        for (int r = 0; r < 4; r++) {
            float mx = acc[0][r];
#pragma unroll
            for (int tt = 1; tt < 24; tt++) mx = fmaxf(mx, acc[tt][r]);
            mx = fmaxf(mx, __shfl_xor(mx, 1));
            mx = fmaxf(mx, __shfl_xor(mx, 2));
            mx = fmaxf(mx, __shfl_xor(mx, 4));
            mx = fmaxf(mx, __shfl_xor(mx, 8));
            float sum = 0.f;
#pragma unroll
            for (int tt = 0; tt < 24; tt++) {
                float p = __expf(acc[tt][r] - mx);
                acc[tt][r] = p;
                sum += p;
            }
            sum += __shfl_xor(sum, 1);
            sum += __shfl_xor(sum, 2);
            sum += __shfl_xor(sum, 4);
            sum += __shfl_xor(sum, 8);
            l[r] = sum;
        }
        f32x4 o0 = {0.f, 0.f, 0.f, 0.f}, o1 = {0.f, 0.f, 0.f, 0.f};
        for (int cc = 0; cc < 4; cc++) {
#pragma unroll
            for (int tt6 = 0; tt6 < 6; tt6++) {
                int tt = cc * 6 + tt6;
#pragma unroll
                for (int r = 0; r < 4; r++)
                    Pw[quad * 4 + r][tt6 * 16 + ln] = acc[tt][r];
            }
#pragma unroll
            for (int kk = 0; kk < 3; kk++) {
                f32x4 plo = *(f32x4*)&Pw[ln][kk * 32 + quad * 8];
                f32x4 phi = *(f32x4*)&Pw[ln][kk * 32 + quad * 8 + 4];
                short8 ap;
#pragma unroll
                for (int j = 0; j < 4; j++) {
                    ap[j]     = f2bs(plo[j]);
                    ap[4 + j] = f2bs(phi[j]);
                }
                int kg = cc * 96 + kk * 32;
                short8 bv0 = *(const short8*)&Vt[ln][kg + quad * 8];
                short8 bv1 = *(const short8*)&Vt[16 + ln][kg + quad * 8];
                o0 = __builtin_amdgcn_mfma_f32_16x16x32_bf16(ap, bv0, o0, 0, 0, 0);
                o1 = __builtin_amdgcn_mfma_f32_16x16x32_bf16(ap, bv1, o1, 0, 0, 0);
            }
        }
#pragma unroll
        for (int r = 0; r < 4; r++) {
            int mrow = quad * 4 + r;
            int rw = s * R + q0 + mrow;
            float invl = 1.0f / l[r];
            size_t base = (size_t)rw * E + h * D;
            float g0 = bs2f(gb[base + ln]);
            float g1 = bs2f(gb[base + 16 + ln]);
            og[base + ln]      = o0[r] * invl * g0;
            og[base + 16 + ln] = o1[r] * invl * g1;
        }
    }
}

// ---------------------------------------------------------------------------
// K4: out = og @ wo + bo via split-bf16 MFMA (unchanged from round 3)
// ---------------------------------------------------------------------------
__global__ __launch_bounds__(256, 2) void k_outproj(
    const float* __restrict__ og, const unsigned short* __restrict__ wot_hi,
    const unsigned short* __restrict__ wot_lo, const float* __restrict__ bo,
    float* __restrict__ out)
{
    __shared__ unsigned int otb[64][260];
    const int t = threadIdx.x;
    const int row0 = blockIdx.x * 64;
#pragma unroll
    for (int i = 0; i < 16; i++) {
        int e4 = i * 256 + t;
        int r = e4 >> 6, c = (e4 & 63) * 4;
        f32x4 v = *(const f32x4*)(og + (size_t)(row0 + r) * E + c);
        u32x4 pk;
        pk[0] = packhl(v[0]); pk[1] = packhl(v[1]);
        pk[2] = packhl(v[2]); pk[3] = packhl(v[3]);
        *(u32x4*)&otb[r][c] = pk;
    }
    __syncthreads();

    const int w = t >> 6, lane = t & 63, ln = lane & 15, quad = lane >> 4;
    const int nbase = w * 64;
    f32x4 acc[4][4];
#pragma unroll
    for (int a = 0; a < 4; a++)
#pragma unroll
        for (int b = 0; b < 4; b++) acc[a][b] = (f32x4){0.f, 0.f, 0.f, 0.f};

    for (int kk = 0; kk < 8; kk++) {
        const int kcol = kk * 32 + quad * 8;
        short8 ah[4], al[4];
#pragma unroll
        for (int mt = 0; mt < 4; mt++) {
            const unsigned int* up = &otb[mt * 16 + ln][kcol];
            u32x4 u0 = *(const u32x4*)up;
            u32x4 u1 = *(const u32x4*)(up + 4);
            U8 A, L;
            A.u[0] = (u0[0] & 0xffffu) | (u0[1] << 16);
            A.u[1] = (u0[2] & 0xffffu) | (u0[3] << 16);
            A.u[2] = (u1[0] & 0xffffu) | (u1[1] << 16);
            A.u[3] = (u1[2] & 0xffffu) | (u1[3] << 16);
            L.u[0] = (u0[0] >> 16) | (u0[1] & 0xffff0000u);
            L.u[1] = (u0[2] >> 16) | (u0[3] & 0xffff0000u);
            L.u[2] = (u1[0] >> 16) | (u1[1] & 0xffff0000u);
            L.u[3] = (u1[2] >> 16) | (u1[3] & 0xffff0000u);
            ah[mt] = A.s; al[mt] = L.s;
        }
#pragma unroll
        for (int nt = 0; nt < 4; nt++) {
            size_t boff = (size_t)(nbase + nt * 16 + ln) * 256 + kcol;
            short8 bh = *(const short8*)(wot_hi + boff);
            short8 bl = *(const short8*)(wot_lo + boff);
#pragma unroll
            for (int mt = 0; mt < 4; mt++) {
                acc[mt][nt] = __builtin_amdgcn_mfma_f32_16x16x32_bf16(ah[mt], bh, acc[mt][nt], 0, 0, 0);
                acc[mt][nt] = __builtin_amdgcn_mfma_f32_16x16x32_bf16(al[mt], bh, acc[mt][nt], 0, 0, 0);
                acc[mt][nt] = __builtin_amdgcn_mfma_f32_16x16x32_bf16(ah[mt], bl, acc[mt][nt], 0, 0, 0);
            }
        }
    }
    const int p = ln & 3;
#pragma unroll
    for (int mt = 0; mt < 4; mt++) {
        int rowg = row0 + mt * 16 + quad * 4 + p;
#pragma unroll
        for (int nt = 0; nt < 4; nt++) {
            int c0 = nbase + nt * 16 + (ln & 12);
            f32x4 a = acc[mt][nt];
            float x0 = a[0], x1 = a[1], x2 = a[2], x3 = a[3];
            xpose4(x0, x1, x2, x3, p);
            float4 bov = *(const float4*)(bo + c0);
            f32x4 o;
            o[0] = x0 + bov.x; o[1] = x1 + bov.y;
            o[2] = x2 + bov.z; o[3] = x3 + bov.w;
            *(f32x4*)(out + (size_t)rowg * CIN + c0) = o;
        }
    }
}

// ---------------------------------------------------------------------------
extern "C" void kernel_launch(void* const* d_in, const int* in_sizes, int n_in,
                              void* d_out, int out_size, void* d_ws, size_t ws_size,
                              hipStream_t stream)
{
    const float* m      = (const float*)d_in[0];
    const float* z      = (const float*)d_in[1];
    const float* mask   = (const float*)d_in[2];
    const float* ln_m_w = (const float*)d_in[3];
    const float* ln_m_b = (const float*)d_in[4];
    const float* ln_z_w = (const float*)d_in[5];
    const float* ln_z_b = (const float*)d_in[6];
    const float* w_pair = (const float*)d_in[7];
    const float* wq     = (const float*)d_in[8];
    const float* wk     = (const float*)d_in[9];
    const float* wv     = (const float*)d_in[10];
    const float* wg     = (const float*)d_in[11];
    const float* bg     = (const float*)d_in[12];
    const float* wo     = (const float*)d_in[13];
    const float* bo     = (const float*)d_in[14];
    float* out = (float*)d_out;

    char* ws = (char*)d_ws;
    float*          pbuf   = (float*)ws;              ws += 4718592;
    unsigned short* qb     = (unsigned short*)ws;     ws += 25165824;
    unsigned short* kb     = (unsigned short*)ws;     ws += 25165824;
    unsigned short* vtb    = (unsigned short*)ws;     ws += 25165824;
    unsigned short* gbuf   = (unsigned short*)ws;     ws += 25165824;
    float*          ogb    = (float*)ws;              ws += 50331648;
    unsigned short* wt_hi  = (unsigned short*)ws;     ws += 524288;
    unsigned short* wt_lo  = (unsigned short*)ws;     ws += 524288;
    unsigned short* wot_hi = (unsigned short*)ws;     ws += 131072;
    unsigned short* wot_lo = (unsigned short*)ws;     ws += 131072;

    k_prepw<<<dim3(320), dim3(256), 0, stream>>>(wq, wk, wv, wg, wo,
                                                 wt_hi, wt_lo, wot_hi, wot_lo);
    k_pairbias<<<dim3(R * R / 4), dim3(256), 0, stream>>>(z, ln_z_w, ln_z_b, w_pair, pbuf);
    k_proj<<<dim3(768), dim3(256), 0, stream>>>(m, ln_m_w, ln_m_b,
                                                wt_hi, wt_lo, bg, qb, kb, vtb, gbuf);
    k_attn<<<dim3(S * H), dim3(256), 0, stream>>>(qb, kb, vtb, gbuf, pbuf, mask, ogb);
    k_outproj<<<dim3(768), dim3(256), 0, stream>>>(ogb, wot_hi, wot_lo, bo, out);
}